// Round 9
// baseline (2083.931 us; speedup 1.0000x reference)
//
#include <hip/hip_runtime.h>
#include <hip/hip_fp16.h>
#include <math.h>

#define B_ 2
#define S_ 1024
#define D_ 512
#define H_ 8
#define P_ 16
#define DH_ 64
#define HP3_ 384
#define CONCAT_ 896
#define CUTOFF 15.0f
#define SCALE_ 0.125f   // DH^-0.5 = 1/8
#define QT 16
#define KT 64
// LDS half strides (in halves): data + pad, rows 16B-aligned
#define HQ 72     // Q: 64 + 8
#define HQP 56    // QP': 48 + 8
#define HK 72     // K: 64 + 8
#define HKP 56    // KP': 48 + 8
#define HV 112    // V|VP: 112 (224B, aligned, no pad needed)
#define HW 72     // weights: 64 + 8

// ---------------------------------------------------------------- helpers
__device__ __forceinline__ float waveReduceSum(float v) {
#pragma unroll
    for (int o = 32; o; o >>= 1) v += __shfl_down(v, o, 64);
    return v;
}
// 8-dim fp16 dot (a,b = 4 half2), fp32 accumulate; compiler folds cvt into v_fma_mix
__device__ __forceinline__ float dot8h(const __half2* a, const __half2* b, float acc) {
#pragma unroll
    for (int i = 0; i < 4; i++) {
        acc = fmaf(__low2float(a[i]),  __low2float(b[i]),  acc);
        acc = fmaf(__high2float(a[i]), __high2float(b[i]), acc);
    }
    return acc;
}

// ---------------------------------------------------------------- kernel 1: LN (LN1 and LN2)
__global__ __launch_bounds__(256) void ln1_kernel(
    const float* __restrict__ x, const float* __restrict__ g,
    const float* __restrict__ b, float* __restrict__ xn) {
    const int row = blockIdx.x;
    const int t = threadIdx.x;
    const float* xr = x + row * D_;
    float x0 = xr[t], x1 = xr[t + 256];
    __shared__ float red[4];
    float s = waveReduceSum(x0 + x1);
    int lane = t & 63, wid = t >> 6;
    if (lane == 0) red[wid] = s;
    __syncthreads();
    float mean = (red[0] + red[1] + red[2] + red[3]) * (1.0f / D_);
    __syncthreads();
    float d0 = x0 - mean, d1 = x1 - mean;
    float v = waveReduceSum(d0 * d0 + d1 * d1);
    if (lane == 0) red[wid] = v;
    __syncthreads();
    float var = (red[0] + red[1] + red[2] + red[3]) * (1.0f / D_);
    float rs = rsqrtf(var + 1e-5f);
    xn[row * D_ + t]       = d0 * rs * g[t] + b[t];
    xn[row * D_ + t + 256] = d1 * rs * g[t + 256] + b[t + 256];
}

// ---------------------------------------------------------------- kernel 2: projections GEMM
// Epilogue writes fp16 copies ONCE (R8 lesson: never convert per-tile in attn):
//  qh,kh: [row][512] fp16 ; qph,kph: [row][384] fp16 = raw + bias (NO coords);
//  vch:   [row][H*112] fp16 (v | vp per head).
__global__ __launch_bounds__(256) void proj_kernel(
    const float* __restrict__ xn, const float* __restrict__ coords,
    const float* __restrict__ Wq, const float* __restrict__ Wk, const float* __restrict__ Wv,
    const float* __restrict__ Wqp, const float* __restrict__ bqp,
    const float* __restrict__ Wkp, const float* __restrict__ bkp,
    const float* __restrict__ Wvp, const float* __restrict__ bvp,
    __half* __restrict__ qh, __half* __restrict__ kh, __half* __restrict__ vch,
    __half* __restrict__ qph, __half* __restrict__ kph) {
    const int tid = threadIdx.x;
    const int rowBase = blockIdx.y * 64;
    const int colBase = blockIdx.x * 64;

    const float* Wseg; int ldw, segBase, segId;
    if      (colBase < 512)  { Wseg = Wq;  ldw = D_;   segBase = 0;    segId = 0; }
    else if (colBase < 1024) { Wseg = Wk;  ldw = D_;   segBase = 512;  segId = 1; }
    else if (colBase < 1536) { Wseg = Wv;  ldw = D_;   segBase = 1024; segId = 2; }
    else if (colBase < 1920) { Wseg = Wqp; ldw = HP3_; segBase = 1536; segId = 3; }
    else if (colBase < 2304) { Wseg = Wkp; ldw = HP3_; segBase = 1920; segId = 4; }
    else                     { Wseg = Wvp; ldw = HP3_; segBase = 2304; segId = 5; }
    const int segc0 = colBase - segBase;

    __shared__ float As[16][65];
    __shared__ float Bs[16][64];
    const int tx = tid & 15, ty = tid >> 4;

    float acc[4][4];
#pragma unroll
    for (int i = 0; i < 4; i++)
#pragma unroll
        for (int j = 0; j < 4; j++) acc[i][j] = 0.f;

    for (int k0 = 0; k0 < D_; k0 += 16) {
#pragma unroll
        for (int i = 0; i < 4; i++) {
            int e = tid + i * 256;
            int r = e >> 4, kk = e & 15;
            As[kk][r] = xn[(rowBase + r) * D_ + k0 + kk];
            int c = e & 63, kb = e >> 6;
            Bs[kb][c] = Wseg[(k0 + kb) * ldw + segc0 + c];
        }
        __syncthreads();
#pragma unroll
        for (int kk = 0; kk < 16; kk++) {
            float a[4], bb[4];
#pragma unroll
            for (int i = 0; i < 4; i++) a[i] = As[kk][ty * 4 + i];
#pragma unroll
            for (int j = 0; j < 4; j++) bb[j] = Bs[kk][tx * 4 + j];
#pragma unroll
            for (int i = 0; i < 4; i++)
#pragma unroll
                for (int j = 0; j < 4; j++) acc[i][j] = fmaf(a[i], bb[j], acc[i][j]);
        }
        __syncthreads();
    }

    const int lc0 = segc0 + tx * 4;   // 4-aligned; never crosses 48/64 head boundaries
#pragma unroll
    for (int i = 0; i < 4; i++) {
        int r = rowBase + ty * 4 + i;
        float v0 = acc[i][0], v1 = acc[i][1], v2 = acc[i][2], v3 = acc[i][3];
        __half2* dst;
        switch (segId) {
            case 0: dst = (__half2*)(qh + (size_t)r * D_ + lc0); break;
            case 1: dst = (__half2*)(kh + (size_t)r * D_ + lc0); break;
            case 2: { int hh = lc0 >> 6, d = lc0 & 63;
                      dst = (__half2*)(vch + (size_t)r * (H_*112) + hh * 112 + d); break; }
            case 3: v0 += bqp[lc0]; v1 += bqp[lc0+1]; v2 += bqp[lc0+2]; v3 += bqp[lc0+3];
                    dst = (__half2*)(qph + (size_t)r * HP3_ + lc0); break;
            case 4: v0 += bkp[lc0]; v1 += bkp[lc0+1]; v2 += bkp[lc0+2]; v3 += bkp[lc0+3];
                    dst = (__half2*)(kph + (size_t)r * HP3_ + lc0); break;
            default: { v0 += bvp[lc0]; v1 += bvp[lc0+1]; v2 += bvp[lc0+2]; v3 += bvp[lc0+3];
                      int hh = lc0 / 48, d = lc0 % 48;
                      dst = (__half2*)(vch + (size_t)r * (H_*112) + hh * 112 + 64 + d); break; }
        }
        dst[0] = __floats2half2_rn(v0, v1);
        dst[1] = __floats2half2_rn(v2, v3);
    }
}

// ---------------------------------------------------------------- kernel 3: per-(row,h) stats
// qstat/kstat[row*H+h] = {s0,s1,s2, A} with s = sum_p p', A = -0.5*sum p'^2 - c.s
__global__ __launch_bounds__(256) void stat_kernel(
    const __half* __restrict__ qph, const __half* __restrict__ kph,
    const float* __restrict__ coords,
    float* __restrict__ qstat, float* __restrict__ kstat) {
    int idx = blockIdx.x * 256 + threadIdx.x;      // 16384
    int row = idx >> 3, h = idx & 7;
    float c0 = coords[row*3], c1 = coords[row*3+1], c2 = coords[row*3+2];
    const __half* qp = qph + (size_t)row * HP3_ + h * 48;
    const __half* kp = kph + (size_t)row * HP3_ + h * 48;
    float s0=0,s1=0,s2=0,n=0;
#pragma unroll
    for (int p = 0; p < 16; p++) {
        float a0 = __half2float(qp[p*3]), a1 = __half2float(qp[p*3+1]), a2 = __half2float(qp[p*3+2]);
        s0 += a0; s1 += a1; s2 += a2;
        n = fmaf(a0,a0,fmaf(a1,a1,fmaf(a2,a2,n)));
    }
    float4* qs4 = (float4*)(qstat + idx*4);
    *qs4 = make_float4(s0, s1, s2, -0.5f*n - (c0*s0 + c1*s1 + c2*s2));
    s0=0; s1=0; s2=0; n=0;
#pragma unroll
    for (int p = 0; p < 16; p++) {
        float a0 = __half2float(kp[p*3]), a1 = __half2float(kp[p*3+1]), a2 = __half2float(kp[p*3+2]);
        s0 += a0; s1 += a1; s2 += a2;
        n = fmaf(a0,a0,fmaf(a1,a1,fmaf(a2,a2,n)));
    }
    float4* ks4 = (float4*)(kstat + idx*4);
    *ks4 = make_float4(s0, s1, s2, -0.5f*n - (c0*s0 + c1*s1 + c2*s2));
}

// ---------------------------------------------------------------- kernel 4: flash attention, fp16 LDS, QT=16
// 1024 blocks -> 4 blocks/CU (LDS 39.7KB). Thread: qr = tid>>4 (one q row), sub = tid&15.
// point term decomposed: Aq + Ak + pd' + cq.ks + ck.qs - 8*dist^2  (all fp16-safe dots).
__global__ __launch_bounds__(256, 4) void attn_kernel(
    const __half* __restrict__ qh, const __half* __restrict__ kh, const __half* __restrict__ vch,
    const __half* __restrict__ qph, const __half* __restrict__ kph,
    const float* __restrict__ qstat, const float* __restrict__ kstat,
    const float* __restrict__ coords,
    const float* __restrict__ Wd1, const float* __restrict__ bd1,
    const float* __restrict__ Wd2, const float* __restrict__ bd2,
    float* __restrict__ attn_out) {
    const int qt = blockIdx.x, h = blockIdx.y, b = blockIdx.z;
    const int tid = threadIdx.x;
    const int qr = tid >> 4;           // 0..15: this thread's q row
    const int sub = tid & 15;          // logits: key = sub+16j ; PV: dim-group
    const int qbase = qt * QT;
    const size_t bq = (size_t)(b * S_ + qbase);

    __shared__ __align__(16) __half sQh[QT * HQ];
    __shared__ __align__(16) __half sQPh[QT * HQP];
    __shared__ __align__(16) __half sKh[KT * HK];
    __shared__ __align__(16) __half sKPh[KT * HKP];
    __shared__ __align__(16) __half sVh[KT * HV];
    __shared__ __align__(16) __half sWh[QT * HW];
    __shared__ __align__(16) float  sKS[KT * 8];   // {ck0,ck1,ck2,-, ks0,ks1,ks2,Ak}
    __shared__ float sW1[32], sB1[32], sW2h[32];

    // ---- stage Q-side once (plain fp16 copies, no conversion)
    if (tid < 128) {      // 16 rows x 8 uint4 of Q
        int r = tid >> 3, c = tid & 7;
        ((uint4*)&sQh[r * HQ])[c] = ((const uint4*)(qh + (bq + r) * D_ + h * DH_))[c];
    } else if (tid < 224) {  // 96 = 16 rows x 6 uint4 of QP'
        int e = tid - 128;
        int r = e / 6, c = e % 6;
        ((uint4*)&sQPh[r * HQP])[c] = ((const uint4*)(qph + (bq + r) * HP3_ + h * 48))[c];
    } else if (tid < 256) {
        int e = tid - 224;   // 32
        sW1[e] = Wd1[e];
        sB1[e] = bd1[e];
        sW2h[e] = Wd2[e * H_ + h];
    }
    // per-thread q-side scalars
    const float4 qst = *(const float4*)(qstat + ((bq + qr) * H_ + h) * 4);
    const float cqx = coords[(bq + qr) * 3], cqy = coords[(bq + qr) * 3 + 1], cqz = coords[(bq + qr) * 3 + 2];
    const float bd2h = bd2[h];
    __syncthreads();

    float m = -3.0e38f, l = 0.f;
    float o[8] = {0,0,0,0,0,0,0,0};

    for (int kt = 0; kt < S_ / KT; kt++) {
        const size_t bk = (size_t)(b * S_ + kt * KT);
        // ---- stage K (2/thr), KP' (1.5/thr), V (3.5/thr), stats (tid<64)
#pragma unroll
        for (int i = 0; i < 2; i++) {
            int f4 = tid + i * 256;   // 512 = 64x8
            int r = f4 >> 3, c = f4 & 7;
            ((uint4*)&sKh[r * HK])[c] = ((const uint4*)(kh + (bk + r) * D_ + h * DH_))[c];
        }
#pragma unroll
        for (int i = 0; i < 2; i++) {
            int f4 = tid + i * 256;   // 384 = 64x6
            if (f4 < 384) {
                int r = f4 / 6, c = f4 % 6;
                ((uint4*)&sKPh[r * HKP])[c] = ((const uint4*)(kph + (bk + r) * HP3_ + h * 48))[c];
            }
        }
#pragma unroll
        for (int i = 0; i < 4; i++) {
            int f4 = tid + i * 256;   // 896 = 64x14
            if (f4 < 896) {
                int r = f4 / 14, c = f4 % 14;
                ((uint4*)&sVh[r * HV])[c] = ((const uint4*)(vch + (bk + r) * (H_*112) + h * 112))[c];
            }
        }
        if (tid < KT) {
            *(float4*)&sKS[tid * 8 + 4] = *(const float4*)(kstat + ((bk + tid) * H_ + h) * 4);
            sKS[tid * 8 + 0] = coords[(bk + tid) * 3];
            sKS[tid * 8 + 1] = coords[(bk + tid) * 3 + 1];
            sKS[tid * 8 + 2] = coords[(bk + tid) * 3 + 2];
        }
        __syncthreads();                  // SYNC-K

        // ---- per-key base term + dist (4 keys: sub+16j)
        float lg[4];
#pragma unroll
        for (int j = 0; j < 4; j++) {
            const int kk = sub + 16 * j;
            float4 c4 = *(const float4*)&sKS[kk * 8];
            float4 s4 = *(const float4*)&sKS[kk * 8 + 4];
            float dx = cqx - c4.x, dy = cqy - c4.y, dz = cqz - c4.z;
            float d2 = fmaf(dx, dx, fmaf(dy, dy, dz * dz));
            float dist = sqrtf(d2);
            // dist-MLP bias
            float bias = bd2h;
#pragma unroll 8
            for (int jj = 0; jj < 32; jj++) {
                float hd = fmaf(dist, sW1[jj], sB1[jj]);
                bias = fmaf(fmaxf(hd, 0.f), sW2h[jj], bias);
            }
            // decomposed point base: Aq + Ak + cq.ks + ck.qs - 8 d2
            float base = qst.w + s4.w
                       + cqx * s4.x + cqy * s4.y + cqz * s4.z
                       + c4.x * qst.x + c4.y * qst.y + c4.z * qst.z
                       - 8.0f * d2 + bias;
            lg[j] = (dist < CUTOFF) ? base : -1e9f;
        }
        // ---- qk dot (fp16 x fp16 -> fp32 via fma_mix)
        {
            const __half2* q2 = (const __half2*)&sQh[qr * HQ];
            float acc[4] = {0,0,0,0};
#pragma unroll
            for (int d8 = 0; d8 < 8; d8++) {
#pragma unroll
                for (int j = 0; j < 4; j++) {
                    const __half2* k2 = (const __half2*)&sKh[(sub + 16 * j) * HK];
                    acc[j] = dot8h(q2 + d8 * 4, k2 + d8 * 4, acc[j]);
                }
            }
            const __half2* p2 = (const __half2*)&sQPh[qr * HQP];
            float pda[4] = {0,0,0,0};
#pragma unroll
            for (int d8 = 0; d8 < 6; d8++) {
#pragma unroll
                for (int j = 0; j < 4; j++) {
                    const __half2* kp2 = (const __half2*)&sKPh[(sub + 16 * j) * HKP];
                    pda[j] = dot8h(p2 + d8 * 4, kp2 + d8 * 4, pda[j]);
                }
            }
#pragma unroll
            for (int j = 0; j < 4; j++)
                if (lg[j] != -1e9f) lg[j] += fmaf(SCALE_, acc[j], pda[j]);
        }
        // ---- wave-local online softmax (16-lane group shares q row)
        float t0 = fmaxf(fmaxf(lg[0], lg[1]), fmaxf(lg[2], lg[3]));
#pragma unroll
        for (int off = 1; off < 16; off <<= 1) t0 = fmaxf(t0, __shfl_xor(t0, off, 16));
        const float nm = fmaxf(m, t0);
        const float sc = __expf(m - nm);
        m = nm;
        float ps = 0.f;
        __half* wrow = &sWh[qr * HW];
#pragma unroll
        for (int j = 0; j < 4; j++) {
            float w = __expf(lg[j] - nm);
            wrow[sub + 16 * j] = __float2half(w);   // same-wave write/read
            ps += w;
        }
#pragma unroll
        for (int off = 1; off < 16; off <<= 1) ps += __shfl_xor(ps, off, 16);
        l = l * sc + ps;

        // ---- PV: 1 q x 8 dims per thread (sub<14), fp16 V + fp16 w
#pragma unroll
        for (int j = 0; j < 8; j++) o[j] *= sc;
        if (sub < 14) {
            const int db = sub * 8;
            for (int kk4 = 0; kk4 < 16; kk4++) {
                __half2 w01 = ((const __half2*)wrow)[kk4 * 2];
                __half2 w23 = ((const __half2*)wrow)[kk4 * 2 + 1];
                float wf[4] = { __low2float(w01), __high2float(w01),
                                __low2float(w23), __high2float(w23) };
#pragma unroll
                for (int jj = 0; jj < 4; jj++) {
                    const __half2* v2 = (const __half2*)&sVh[(kk4 * 4 + jj) * HV + db];
                    float w = wf[jj];
                    o[0] = fmaf(w, __low2float(v2[0]),  o[0]);
                    o[1] = fmaf(w, __high2float(v2[0]), o[1]);
                    o[2] = fmaf(w, __low2float(v2[1]),  o[2]);
                    o[3] = fmaf(w, __high2float(v2[1]), o[3]);
                    o[4] = fmaf(w, __low2float(v2[2]),  o[4]);
                    o[5] = fmaf(w, __high2float(v2[2]), o[5]);
                    o[6] = fmaf(w, __low2float(v2[3]),  o[6]);
                    o[7] = fmaf(w, __high2float(v2[3]), o[7]);
                }
            }
        }
        __syncthreads();                  // SYNC-C (next staging overwrites)
    }

    // ---- epilogue
    if (sub < 14) {
        const int db = sub * 8;
        const float il = 1.0f / l;
        const int off = (db < 64) ? (h * 64 + db) : (512 + h * 48 + (db - 64));
        float* r0 = attn_out + (size_t)(bq + qr) * CONCAT_ + off;
        float4 a, bqt;
        a.x = o[0]*il; a.y = o[1]*il; a.z = o[2]*il; a.w = o[3]*il;
        bqt.x = o[4]*il; bqt.y = o[5]*il; bqt.z = o[6]*il; bqt.w = o[7]*il;
        *(float4*)r0 = a; *(float4*)(r0 + 4) = bqt;
    }
}

// ---------------------------------------------------------------- kernel 5: out projection GEMM (+bias+residual)
__global__ __launch_bounds__(256) void ogemm_kernel(
    const float* __restrict__ aout, const float* __restrict__ x,
    const float* __restrict__ Wo, const float* __restrict__ bo,
    float* __restrict__ yres) {
    const int tid = threadIdx.x;
    const int rowBase = blockIdx.y * 64;
    const int colBase = blockIdx.x * 64;

    __shared__ float As[16][65];
    __shared__ float Bs[16][64];
    const int tx = tid & 15, ty = tid >> 4;

    float acc[4][4];
#pragma unroll
    for (int i = 0; i < 4; i++)
#pragma unroll
        for (int j = 0; j < 4; j++) acc[i][j] = 0.f;

    for (int k0 = 0; k0 < CONCAT_; k0 += 16) {
#pragma unroll
        for (int i = 0; i < 4; i++) {
            int e = tid + i * 256;
            int r = e >> 4, kk = e & 15;
            As[kk][r] = aout[(size_t)(rowBase + r) * CONCAT_ + k0 + kk];
            int c = e & 63, kb = e >> 6;
            Bs[kb][c] = Wo[(k0 + kb) * D_ + colBase + c];
        }
        __syncthreads();
#pragma unroll
        for (int kk = 0; kk < 16; kk++) {
            float a[4], bb[4];
#pragma unroll
            for (int i = 0; i < 4; i++) a[i] = As[kk][ty * 4 + i];
#pragma unroll
            for (int j = 0; j < 4; j++) bb[j] = Bs[kk][tx * 4 + j];
#pragma unroll
            for (int i = 0; i < 4; i++)
#pragma unroll
                for (int j = 0; j < 4; j++) acc[i][j] = fmaf(a[i], bb[j], acc[i][j]);
        }
        __syncthreads();
    }

#pragma unroll
    for (int i = 0; i < 4; i++) {
        int r = rowBase + ty * 4 + i;
#pragma unroll
        for (int j = 0; j < 4; j++) {
            int lc = colBase + tx * 4 + j;
            yres[(size_t)r * D_ + lc] = acc[i][j] + bo[lc] + x[(size_t)r * D_ + lc];
        }
    }
}

// ---------------------------------------------------------------- kernel 6: coord update
__global__ __launch_bounds__(64) void coord_kernel(
    const float* __restrict__ aout, const float* __restrict__ coords,
    float* __restrict__ coords_out) {
    const int row = blockIdx.x;
    const int t = threadIdx.x;
    const float* ap = aout + (size_t)row * CONCAT_ + 512;
    float c0 = ap[t * 3]     + ap[(t + 64) * 3];
    float c1 = ap[t * 3 + 1] + ap[(t + 64) * 3 + 1];
    float c2 = ap[t * 3 + 2] + ap[(t + 64) * 3 + 2];
#pragma unroll
    for (int o = 32; o; o >>= 1) {
        c0 += __shfl_down(c0, o, 64);
        c1 += __shfl_down(c1, o, 64);
        c2 += __shfl_down(c2, o, 64);
    }
    if (t == 0) {
        coords_out[row * 3 + 0] = coords[row * 3 + 0] + c0 * (0.1f / 128.f);
        coords_out[row * 3 + 1] = coords[row * 3 + 1] + c1 * (0.1f / 128.f);
        coords_out[row * 3 + 2] = coords[row * 3 + 2] + c2 * (0.1f / 128.f);
    }
}

// ---------------------------------------------------------------- launch
extern "C" void kernel_launch(void* const* d_in, const int* in_sizes, int n_in,
                              void* d_out, int out_size, void* d_ws, size_t ws_size,
                              hipStream_t stream) {
    const float* x      = (const float*)d_in[0];
    const float* coords = (const float*)d_in[1];
    const float* Wq     = (const float*)d_in[2];
    const float* Wk     = (const float*)d_in[3];
    const float* Wv     = (const float*)d_in[4];
    const float* Wqp    = (const float*)d_in[5];
    const float* bqp    = (const float*)d_in[6];
    const float* Wkp    = (const float*)d_in[7];
    const float* bkp    = (const float*)d_in[8];
    const float* Wvp    = (const float*)d_in[9];
    const float* bvp    = (const float*)d_in[10];
    const float* Wd1    = (const float*)d_in[11];
    const float* bd1    = (const float*)d_in[12];
    const float* Wd2    = (const float*)d_in[13];
    const float* bd2    = (const float*)d_in[14];
    const float* Wo     = (const float*)d_in[15];
    const float* bo     = (const float*)d_in[16];
    const float* g1     = (const float*)d_in[17];
    const float* b1     = (const float*)d_in[18];
    const float* g2     = (const float*)d_in[19];
    const float* b2     = (const float*)d_in[20];

    float* out        = (float*)d_out;
    float* coords_out = (float*)d_out + (size_t)B_ * S_ * D_;

    const size_t NROW = (size_t)B_ * S_;
    float* ws    = (float*)d_ws;
    float* xn    = ws;                            // NROW*512 f32 (reused as yres)
    float* aout  = xn + NROW * D_;                // NROW*896 f32
    __half* qh   = (__half*)(aout + NROW * CONCAT_);   // NROW*512 fp16
    __half* kh   = qh  + NROW * D_;
    __half* qph  = kh  + NROW * D_;               // NROW*384
    __half* kph  = qph + NROW * HP3_;
    __half* vch  = kph + NROW * HP3_;             // NROW*896
    float* qstat = (float*)(vch + NROW * (H_*112));    // NROW*8*4 f32
    float* kstat = qstat + NROW * H_ * 4;

    ln1_kernel<<<NROW, 256, 0, stream>>>(x, g1, b1, xn);

    dim3 pgrid(2688 / 64, 2048 / 64);
    proj_kernel<<<pgrid, 256, 0, stream>>>(xn, coords, Wq, Wk, Wv,
                                           Wqp, bqp, Wkp, bkp, Wvp, bvp,
                                           qh, kh, vch, qph, kph);

    stat_kernel<<<(NROW * H_) / 256, 256, 0, stream>>>(qph, kph, coords, qstat, kstat);

    dim3 agrid(S_ / QT, H_, B_);
    attn_kernel<<<agrid, 256, 0, stream>>>(qh, kh, vch, qph, kph, qstat, kstat,
                                           coords, Wd1, bd1, Wd2, bd2, aout);

    float* yres = xn;
    dim3 ogrid(D_ / 64, 2048 / 64);
    ogemm_kernel<<<ogrid, 256, 0, stream>>>(aout, x, Wo, bo, yres);

    ln1_kernel<<<NROW, 256, 0, stream>>>(yres, g2, b2, out);

    coord_kernel<<<NROW, 64, 0, stream>>>(aout, coords, coords_out);
}

// Round 11
// 1623.824 us; speedup vs baseline: 1.2833x; 1.2833x over previous
//
#include <hip/hip_runtime.h>
#include <hip/hip_fp16.h>
#include <math.h>

#define B_ 2
#define S_ 1024
#define D_ 512
#define H_ 8
#define P_ 16
#define DH_ 64
#define HP3_ 384
#define CONCAT_ 896
#define CUTOFF 15.0f
#define SCALE_ 0.125f   // DH^-0.5 = 1/8
#define QT 16
#define KT 64
// LDS half strides (in halves): data + pad, rows 16B-aligned
#define HQ 72     // Q: 64 + 8
#define HQP 56    // QP': 48 + 8
#define HK 72     // K: 64 + 8
#define HKP 56    // KP': 48 + 8
#define HV 112    // V|VP: 112 (224B, aligned, no pad needed)
#define HW 72     // weights: 64 + 8

// ---------------------------------------------------------------- helpers
__device__ __forceinline__ float waveReduceSum(float v) {
#pragma unroll
    for (int o = 32; o; o >>= 1) v += __shfl_down(v, o, 64);
    return v;
}
// 8-dim fp16 dot (a,b = 4 half2), fp32 accumulate; compiler folds cvt into v_fma_mix
__device__ __forceinline__ float dot8h(const __half2* a, const __half2* b, float acc) {
#pragma unroll
    for (int i = 0; i < 4; i++) {
        acc = fmaf(__low2float(a[i]),  __low2float(b[i]),  acc);
        acc = fmaf(__high2float(a[i]), __high2float(b[i]), acc);
    }
    return acc;
}

// ---------------------------------------------------------------- kernel 1: LN (LN1 and LN2)
__global__ __launch_bounds__(256) void ln1_kernel(
    const float* __restrict__ x, const float* __restrict__ g,
    const float* __restrict__ b, float* __restrict__ xn) {
    const int row = blockIdx.x;
    const int t = threadIdx.x;
    const float* xr = x + row * D_;
    float x0 = xr[t], x1 = xr[t + 256];
    __shared__ float red[4];
    float s = waveReduceSum(x0 + x1);
    int lane = t & 63, wid = t >> 6;
    if (lane == 0) red[wid] = s;
    __syncthreads();
    float mean = (red[0] + red[1] + red[2] + red[3]) * (1.0f / D_);
    __syncthreads();
    float d0 = x0 - mean, d1 = x1 - mean;
    float v = waveReduceSum(d0 * d0 + d1 * d1);
    if (lane == 0) red[wid] = v;
    __syncthreads();
    float var = (red[0] + red[1] + red[2] + red[3]) * (1.0f / D_);
    float rs = rsqrtf(var + 1e-5f);
    xn[row * D_ + t]       = d0 * rs * g[t] + b[t];
    xn[row * D_ + t + 256] = d1 * rs * g[t + 256] + b[t + 256];
}

// ---------------------------------------------------------------- kernel 2: projections GEMM
// Epilogue writes fp16 copies ONCE (R8 lesson: never convert per-tile in attn):
//  qh,kh: [row][512] fp16 ; qph,kph: [row][384] fp16 = raw + bias (NO coords);
//  vch:   [row][H*112] fp16 (v | vp per head).
__global__ __launch_bounds__(256) void proj_kernel(
    const float* __restrict__ xn, const float* __restrict__ coords,
    const float* __restrict__ Wq, const float* __restrict__ Wk, const float* __restrict__ Wv,
    const float* __restrict__ Wqp, const float* __restrict__ bqp,
    const float* __restrict__ Wkp, const float* __restrict__ bkp,
    const float* __restrict__ Wvp, const float* __restrict__ bvp,
    __half* __restrict__ qh, __half* __restrict__ kh, __half* __restrict__ vch,
    __half* __restrict__ qph, __half* __restrict__ kph) {
    const int tid = threadIdx.x;
    const int rowBase = blockIdx.y * 64;
    const int colBase = blockIdx.x * 64;

    const float* Wseg; int ldw, segBase, segId;
    if      (colBase < 512)  { Wseg = Wq;  ldw = D_;   segBase = 0;    segId = 0; }
    else if (colBase < 1024) { Wseg = Wk;  ldw = D_;   segBase = 512;  segId = 1; }
    else if (colBase < 1536) { Wseg = Wv;  ldw = D_;   segBase = 1024; segId = 2; }
    else if (colBase < 1920) { Wseg = Wqp; ldw = HP3_; segBase = 1536; segId = 3; }
    else if (colBase < 2304) { Wseg = Wkp; ldw = HP3_; segBase = 1920; segId = 4; }
    else                     { Wseg = Wvp; ldw = HP3_; segBase = 2304; segId = 5; }
    const int segc0 = colBase - segBase;

    __shared__ float As[16][65];
    __shared__ float Bs[16][64];
    const int tx = tid & 15, ty = tid >> 4;

    float acc[4][4];
#pragma unroll
    for (int i = 0; i < 4; i++)
#pragma unroll
        for (int j = 0; j < 4; j++) acc[i][j] = 0.f;

    for (int k0 = 0; k0 < D_; k0 += 16) {
#pragma unroll
        for (int i = 0; i < 4; i++) {
            int e = tid + i * 256;
            int r = e >> 4, kk = e & 15;
            As[kk][r] = xn[(rowBase + r) * D_ + k0 + kk];
            int c = e & 63, kb = e >> 6;
            Bs[kb][c] = Wseg[(k0 + kb) * ldw + segc0 + c];
        }
        __syncthreads();
#pragma unroll
        for (int kk = 0; kk < 16; kk++) {
            float a[4], bb[4];
#pragma unroll
            for (int i = 0; i < 4; i++) a[i] = As[kk][ty * 4 + i];
#pragma unroll
            for (int j = 0; j < 4; j++) bb[j] = Bs[kk][tx * 4 + j];
#pragma unroll
            for (int i = 0; i < 4; i++)
#pragma unroll
                for (int j = 0; j < 4; j++) acc[i][j] = fmaf(a[i], bb[j], acc[i][j]);
        }
        __syncthreads();
    }

    const int lc0 = segc0 + tx * 4;   // 4-aligned; never crosses 48/64 head boundaries
#pragma unroll
    for (int i = 0; i < 4; i++) {
        int r = rowBase + ty * 4 + i;
        float v0 = acc[i][0], v1 = acc[i][1], v2 = acc[i][2], v3 = acc[i][3];
        __half2* dst;
        switch (segId) {
            case 0: dst = (__half2*)(qh + (size_t)r * D_ + lc0); break;
            case 1: dst = (__half2*)(kh + (size_t)r * D_ + lc0); break;
            case 2: { int hh = lc0 >> 6, d = lc0 & 63;
                      dst = (__half2*)(vch + (size_t)r * (H_*112) + hh * 112 + d); break; }
            case 3: v0 += bqp[lc0]; v1 += bqp[lc0+1]; v2 += bqp[lc0+2]; v3 += bqp[lc0+3];
                    dst = (__half2*)(qph + (size_t)r * HP3_ + lc0); break;
            case 4: v0 += bkp[lc0]; v1 += bkp[lc0+1]; v2 += bkp[lc0+2]; v3 += bkp[lc0+3];
                    dst = (__half2*)(kph + (size_t)r * HP3_ + lc0); break;
            default: { v0 += bvp[lc0]; v1 += bvp[lc0+1]; v2 += bvp[lc0+2]; v3 += bvp[lc0+3];
                      int hh = lc0 / 48, d = lc0 % 48;
                      dst = (__half2*)(vch + (size_t)r * (H_*112) + hh * 112 + 64 + d); break; }
        }
        dst[0] = __floats2half2_rn(v0, v1);
        dst[1] = __floats2half2_rn(v2, v3);
    }
}

// ---------------------------------------------------------------- kernel 3: per-(row,h) stats
// qstat/kstat[row*H+h] = {s0,s1,s2, A} with s = sum_p p', A = -0.5*sum p'^2 - c.s
__global__ __launch_bounds__(256) void stat_kernel(
    const __half* __restrict__ qph, const __half* __restrict__ kph,
    const float* __restrict__ coords,
    float* __restrict__ qstat, float* __restrict__ kstat) {
    int idx = blockIdx.x * 256 + threadIdx.x;      // 16384
    int row = idx >> 3, h = idx & 7;
    float c0 = coords[row*3], c1 = coords[row*3+1], c2 = coords[row*3+2];
    const __half* qp = qph + (size_t)row * HP3_ + h * 48;
    const __half* kp = kph + (size_t)row * HP3_ + h * 48;
    float s0=0,s1=0,s2=0,n=0;
#pragma unroll
    for (int p = 0; p < 16; p++) {
        float a0 = __half2float(qp[p*3]), a1 = __half2float(qp[p*3+1]), a2 = __half2float(qp[p*3+2]);
        s0 += a0; s1 += a1; s2 += a2;
        n = fmaf(a0,a0,fmaf(a1,a1,fmaf(a2,a2,n)));
    }
    float4* qs4 = (float4*)(qstat + idx*4);
    *qs4 = make_float4(s0, s1, s2, -0.5f*n - (c0*s0 + c1*s1 + c2*s2));
    s0=0; s1=0; s2=0; n=0;
#pragma unroll
    for (int p = 0; p < 16; p++) {
        float a0 = __half2float(kp[p*3]), a1 = __half2float(kp[p*3+1]), a2 = __half2float(kp[p*3+2]);
        s0 += a0; s1 += a1; s2 += a2;
        n = fmaf(a0,a0,fmaf(a1,a1,fmaf(a2,a2,n)));
    }
    float4* ks4 = (float4*)(kstat + idx*4);
    *ks4 = make_float4(s0, s1, s2, -0.5f*n - (c0*s0 + c1*s1 + c2*s2));
}

// ---------------------------------------------------------------- kernel 4: flash attention, fp16 LDS, QT=16
// R9 lesson: __launch_bounds__(256,4) capped VGPR at 64 -> 3.3GB spill traffic.
// (256,2) lets the allocator land ~100-125 VGPR (<=128 -> HW still fits 4 blocks/CU
// with the 39.9KB LDS). Thread: qr = tid>>4 (one q row), sub = tid&15.
__global__ __launch_bounds__(256, 2) void attn_kernel(
    const __half* __restrict__ qh, const __half* __restrict__ kh, const __half* __restrict__ vch,
    const __half* __restrict__ qph, const __half* __restrict__ kph,
    const float* __restrict__ qstat, const float* __restrict__ kstat,
    const float* __restrict__ coords,
    const float* __restrict__ Wd1, const float* __restrict__ bd1,
    const float* __restrict__ Wd2, const float* __restrict__ bd2,
    float* __restrict__ attn_out) {
    const int qt = blockIdx.x, h = blockIdx.y, b = blockIdx.z;
    const int tid = threadIdx.x;
    const int qr = tid >> 4;           // 0..15: this thread's q row
    const int sub = tid & 15;          // logits: key = sub+16j ; PV: dim-group
    const int qbase = qt * QT;
    const size_t bq = (size_t)(b * S_ + qbase);

    __shared__ __align__(16) __half sQh[QT * HQ];
    __shared__ __align__(16) __half sQPh[QT * HQP];
    __shared__ __align__(16) __half sKh[KT * HK];
    __shared__ __align__(16) __half sKPh[KT * HKP];
    __shared__ __align__(16) __half sVh[KT * HV];
    __shared__ __align__(16) __half sWh[QT * HW];
    __shared__ __align__(16) float  sKS[KT * 8];   // {ck0,ck1,ck2,-, ks0,ks1,ks2,Ak}
    __shared__ float sW1[32], sB1[32], sW2h[32];

    // ---- stage Q-side once (plain fp16 copies, no conversion)
    if (tid < 128) {      // 16 rows x 8 uint4 of Q
        int r = tid >> 3, c = tid & 7;
        ((uint4*)&sQh[r * HQ])[c] = ((const uint4*)(qh + (bq + r) * D_ + h * DH_))[c];
    } else if (tid < 224) {  // 96 = 16 rows x 6 uint4 of QP'
        int e = tid - 128;
        int r = e / 6, c = e % 6;
        ((uint4*)&sQPh[r * HQP])[c] = ((const uint4*)(qph + (bq + r) * HP3_ + h * 48))[c];
    } else if (tid < 256) {
        int e = tid - 224;   // 32
        sW1[e] = Wd1[e];
        sB1[e] = bd1[e];
        sW2h[e] = Wd2[e * H_ + h];
    }
    // per-thread q-side scalars
    const float4 qst = *(const float4*)(qstat + ((bq + qr) * H_ + h) * 4);
    const float cqx = coords[(bq + qr) * 3], cqy = coords[(bq + qr) * 3 + 1], cqz = coords[(bq + qr) * 3 + 2];
    const float bd2h = bd2[h];
    __syncthreads();

    float m = -3.0e38f, l = 0.f;
    float o[8] = {0,0,0,0,0,0,0,0};

    for (int kt = 0; kt < S_ / KT; kt++) {
        const size_t bk = (size_t)(b * S_ + kt * KT);
        // ---- stage K (2/thr), KP' (1.5/thr), V (3.5/thr), stats (tid<64)
#pragma unroll
        for (int i = 0; i < 2; i++) {
            int f4 = tid + i * 256;   // 512 = 64x8
            int r = f4 >> 3, c = f4 & 7;
            ((uint4*)&sKh[r * HK])[c] = ((const uint4*)(kh + (bk + r) * D_ + h * DH_))[c];
        }
#pragma unroll
        for (int i = 0; i < 2; i++) {
            int f4 = tid + i * 256;   // 384 = 64x6
            if (f4 < 384) {
                int r = f4 / 6, c = f4 % 6;
                ((uint4*)&sKPh[r * HKP])[c] = ((const uint4*)(kph + (bk + r) * HP3_ + h * 48))[c];
            }
        }
#pragma unroll
        for (int i = 0; i < 4; i++) {
            int f4 = tid + i * 256;   // 896 = 64x14
            if (f4 < 896) {
                int r = f4 / 14, c = f4 % 14;
                ((uint4*)&sVh[r * HV])[c] = ((const uint4*)(vch + (bk + r) * (H_*112) + h * 112))[c];
            }
        }
        if (tid < KT) {
            *(float4*)&sKS[tid * 8 + 4] = *(const float4*)(kstat + ((bk + tid) * H_ + h) * 4);
            sKS[tid * 8 + 0] = coords[(bk + tid) * 3];
            sKS[tid * 8 + 1] = coords[(bk + tid) * 3 + 1];
            sKS[tid * 8 + 2] = coords[(bk + tid) * 3 + 2];
        }
        __syncthreads();                  // SYNC-K

        // ---- per-key base term + dist (4 keys: sub+16j)
        float lg[4];
#pragma unroll
        for (int j = 0; j < 4; j++) {
            const int kk = sub + 16 * j;
            float4 c4 = *(const float4*)&sKS[kk * 8];
            float4 s4 = *(const float4*)&sKS[kk * 8 + 4];
            float dx = cqx - c4.x, dy = cqy - c4.y, dz = cqz - c4.z;
            float d2 = fmaf(dx, dx, fmaf(dy, dy, dz * dz));
            float dist = sqrtf(d2);
            // dist-MLP bias
            float bias = bd2h;
#pragma unroll 8
            for (int jj = 0; jj < 32; jj++) {
                float hd = fmaf(dist, sW1[jj], sB1[jj]);
                bias = fmaf(fmaxf(hd, 0.f), sW2h[jj], bias);
            }
            // decomposed point base: Aq + Ak + cq.ks + ck.qs - 8 d2
            float base = qst.w + s4.w
                       + cqx * s4.x + cqy * s4.y + cqz * s4.z
                       + c4.x * qst.x + c4.y * qst.y + c4.z * qst.z
                       - 8.0f * d2 + bias;
            lg[j] = (dist < CUTOFF) ? base : -1e9f;
        }
        // ---- qk dot (fp16 x fp16 -> fp32 via fma_mix)
        {
            const __half2* q2 = (const __half2*)&sQh[qr * HQ];
            float acc[4] = {0,0,0,0};
#pragma unroll
            for (int d8 = 0; d8 < 8; d8++) {
#pragma unroll
                for (int j = 0; j < 4; j++) {
                    const __half2* k2 = (const __half2*)&sKh[(sub + 16 * j) * HK];
                    acc[j] = dot8h(q2 + d8 * 4, k2 + d8 * 4, acc[j]);
                }
            }
            const __half2* p2 = (const __half2*)&sQPh[qr * HQP];
            float pda[4] = {0,0,0,0};
#pragma unroll
            for (int d8 = 0; d8 < 6; d8++) {
#pragma unroll
                for (int j = 0; j < 4; j++) {
                    const __half2* kp2 = (const __half2*)&sKPh[(sub + 16 * j) * HKP];
                    pda[j] = dot8h(p2 + d8 * 4, kp2 + d8 * 4, pda[j]);
                }
            }
#pragma unroll
            for (int j = 0; j < 4; j++)
                if (lg[j] != -1e9f) lg[j] += fmaf(SCALE_, acc[j], pda[j]);
        }
        // ---- wave-local online softmax (16-lane group shares q row)
        float t0 = fmaxf(fmaxf(lg[0], lg[1]), fmaxf(lg[2], lg[3]));
#pragma unroll
        for (int off = 1; off < 16; off <<= 1) t0 = fmaxf(t0, __shfl_xor(t0, off, 16));
        const float nm = fmaxf(m, t0);
        const float sc = __expf(m - nm);
        m = nm;
        float ps = 0.f;
        __half* wrow = &sWh[qr * HW];
#pragma unroll
        for (int j = 0; j < 4; j++) {
            float w = __expf(lg[j] - nm);
            wrow[sub + 16 * j] = __float2half(w);   // same-wave write/read
            ps += w;
        }
#pragma unroll
        for (int off = 1; off < 16; off <<= 1) ps += __shfl_xor(ps, off, 16);
        l = l * sc + ps;

        // ---- PV: 1 q x 8 dims per thread (sub<14), fp16 V + fp16 w
#pragma unroll
        for (int j = 0; j < 8; j++) o[j] *= sc;
        if (sub < 14) {
            const int db = sub * 8;
            for (int kk4 = 0; kk4 < 16; kk4++) {
                __half2 w01 = ((const __half2*)wrow)[kk4 * 2];
                __half2 w23 = ((const __half2*)wrow)[kk4 * 2 + 1];
                float wf[4] = { __low2float(w01), __high2float(w01),
                                __low2float(w23), __high2float(w23) };
#pragma unroll
                for (int jj = 0; jj < 4; jj++) {
                    const __half2* v2 = (const __half2*)&sVh[(kk4 * 4 + jj) * HV + db];
                    float w = wf[jj];
                    o[0] = fmaf(w, __low2float(v2[0]),  o[0]);
                    o[1] = fmaf(w, __high2float(v2[0]), o[1]);
                    o[2] = fmaf(w, __low2float(v2[1]),  o[2]);
                    o[3] = fmaf(w, __high2float(v2[1]), o[3]);
                    o[4] = fmaf(w, __low2float(v2[2]),  o[4]);
                    o[5] = fmaf(w, __high2float(v2[2]), o[5]);
                    o[6] = fmaf(w, __low2float(v2[3]),  o[6]);
                    o[7] = fmaf(w, __high2float(v2[3]), o[7]);
                }
            }
        }
        __syncthreads();                  // SYNC-C (next staging overwrites)
    }

    // ---- epilogue
    if (sub < 14) {
        const int db = sub * 8;
        const float il = 1.0f / l;
        const int off = (db < 64) ? (h * 64 + db) : (512 + h * 48 + (db - 64));
        float* r0 = attn_out + (size_t)(bq + qr) * CONCAT_ + off;
        float4 a, bqt;
        a.x = o[0]*il; a.y = o[1]*il; a.z = o[2]*il; a.w = o[3]*il;
        bqt.x = o[4]*il; bqt.y = o[5]*il; bqt.z = o[6]*il; bqt.w = o[7]*il;
        *(float4*)r0 = a; *(float4*)(r0 + 4) = bqt;
    }
}

// ---------------------------------------------------------------- kernel 5: out projection GEMM (+bias+residual)
__global__ __launch_bounds__(256) void ogemm_kernel(
    const float* __restrict__ aout, const float* __restrict__ x,
    const float* __restrict__ Wo, const float* __restrict__ bo,
    float* __restrict__ yres) {
    const int tid = threadIdx.x;
    const int rowBase = blockIdx.y * 64;
    const int colBase = blockIdx.x * 64;

    __shared__ float As[16][65];
    __shared__ float Bs[16][64];
    const int tx = tid & 15, ty = tid >> 4;

    float acc[4][4];
#pragma unroll
    for (int i = 0; i < 4; i++)
#pragma unroll
        for (int j = 0; j < 4; j++) acc[i][j] = 0.f;

    for (int k0 = 0; k0 < CONCAT_; k0 += 16) {
#pragma unroll
        for (int i = 0; i < 4; i++) {
            int e = tid + i * 256;
            int r = e >> 4, kk = e & 15;
            As[kk][r] = aout[(size_t)(rowBase + r) * CONCAT_ + k0 + kk];
            int c = e & 63, kb = e >> 6;
            Bs[kb][c] = Wo[(k0 + kb) * D_ + colBase + c];
        }
        __syncthreads();
#pragma unroll
        for (int kk = 0; kk < 16; kk++) {
            float a[4], bb[4];
#pragma unroll
            for (int i = 0; i < 4; i++) a[i] = As[kk][ty * 4 + i];
#pragma unroll
            for (int j = 0; j < 4; j++) bb[j] = Bs[kk][tx * 4 + j];
#pragma unroll
            for (int i = 0; i < 4; i++)
#pragma unroll
                for (int j = 0; j < 4; j++) acc[i][j] = fmaf(a[i], bb[j], acc[i][j]);
        }
        __syncthreads();
    }

#pragma unroll
    for (int i = 0; i < 4; i++) {
        int r = rowBase + ty * 4 + i;
#pragma unroll
        for (int j = 0; j < 4; j++) {
            int lc = colBase + tx * 4 + j;
            yres[(size_t)r * D_ + lc] = acc[i][j] + bo[lc] + x[(size_t)r * D_ + lc];
        }
    }
}

// ---------------------------------------------------------------- kernel 6: coord update
__global__ __launch_bounds__(64) void coord_kernel(
    const float* __restrict__ aout, const float* __restrict__ coords,
    float* __restrict__ coords_out) {
    const int row = blockIdx.x;
    const int t = threadIdx.x;
    const float* ap = aout + (size_t)row * CONCAT_ + 512;
    float c0 = ap[t * 3]     + ap[(t + 64) * 3];
    float c1 = ap[t * 3 + 1] + ap[(t + 64) * 3 + 1];
    float c2 = ap[t * 3 + 2] + ap[(t + 64) * 3 + 2];
#pragma unroll
    for (int o = 32; o; o >>= 1) {
        c0 += __shfl_down(c0, o, 64);
        c1 += __shfl_down(c1, o, 64);
        c2 += __shfl_down(c2, o, 64);
    }
    if (t == 0) {
        coords_out[row * 3 + 0] = coords[row * 3 + 0] + c0 * (0.1f / 128.f);
        coords_out[row * 3 + 1] = coords[row * 3 + 1] + c1 * (0.1f / 128.f);
        coords_out[row * 3 + 2] = coords[row * 3 + 2] + c2 * (0.1f / 128.f);
    }
}

// ---------------------------------------------------------------- launch
extern "C" void kernel_launch(void* const* d_in, const int* in_sizes, int n_in,
                              void* d_out, int out_size, void* d_ws, size_t ws_size,
                              hipStream_t stream) {
    const float* x      = (const float*)d_in[0];
    const float* coords = (const float*)d_in[1];
    const float* Wq     = (const float*)d_in[2];
    const float* Wk     = (const float*)d_in[3];
    const float* Wv     = (const float*)d_in[4];
    const float* Wqp    = (const float*)d_in[5];
    const float* bqp    = (const float*)d_in[6];
    const float* Wkp    = (const float*)d_in[7];
    const float* bkp    = (const float*)d_in[8];
    const float* Wvp    = (const float*)d_in[9];
    const float* bvp    = (const float*)d_in[10];
    const float* Wd1    = (const float*)d_in[11];
    const float* bd1    = (const float*)d_in[12];
    const float* Wd2    = (const float*)d_in[13];
    const float* bd2    = (const float*)d_in[14];
    const float* Wo     = (const float*)d_in[15];
    const float* bo     = (const float*)d_in[16];
    const float* g1     = (const float*)d_in[17];
    const float* b1     = (const float*)d_in[18];
    const float* g2     = (const float*)d_in[19];
    const float* b2     = (const float*)d_in[20];

    float* out        = (float*)d_out;
    float* coords_out = (float*)d_out + (size_t)B_ * S_ * D_;

    const size_t NROW = (size_t)B_ * S_;
    float* ws    = (float*)d_ws;
    float* xn    = ws;                            // NROW*512 f32 (reused as yres)
    float* aout  = xn + NROW * D_;                // NROW*896 f32
    __half* qh   = (__half*)(aout + NROW * CONCAT_);   // NROW*512 fp16
    __half* kh   = qh  + NROW * D_;
    __half* qph  = kh  + NROW * D_;               // NROW*384
    __half* kph  = qph + NROW * HP3_;
    __half* vch  = kph + NROW * HP3_;             // NROW*896
    float* qstat = (float*)(vch + NROW * (H_*112));    // NROW*8*4 f32
    float* kstat = qstat + NROW * H_ * 4;

    ln1_kernel<<<NROW, 256, 0, stream>>>(x, g1, b1, xn);

    dim3 pgrid(2688 / 64, 2048 / 64);
    proj_kernel<<<pgrid, 256, 0, stream>>>(xn, coords, Wq, Wk, Wv,
                                           Wqp, bqp, Wkp, bkp, Wvp, bvp,
                                           qh, kh, vch, qph, kph);

    stat_kernel<<<(NROW * H_) / 256, 256, 0, stream>>>(qph, kph, coords, qstat, kstat);

    dim3 agrid(S_ / QT, H_, B_);
    attn_kernel<<<agrid, 256, 0, stream>>>(qh, kh, vch, qph, kph, qstat, kstat,
                                           coords, Wd1, bd1, Wd2, bd2, aout);

    float* yres = xn;
    dim3 ogrid(D_ / 64, 2048 / 64);
    ogemm_kernel<<<ogrid, 256, 0, stream>>>(aout, x, Wo, bo, yres);

    ln1_kernel<<<NROW, 256, 0, stream>>>(yres, g2, b2, out);

    coord_kernel<<<NROW, 64, 0, stream>>>(aout, coords, coords_out);
}

// Round 12
// 629.065 us; speedup vs baseline: 3.3127x; 2.5813x over previous
//
#include <hip/hip_runtime.h>
#include <hip/hip_fp16.h>
#include <math.h>

#define B_ 2
#define S_ 1024
#define D_ 512
#define H_ 8
#define P_ 16
#define DH_ 64
#define HP3_ 384
#define CONCAT_ 896
#define CUTOFF 15.0f
#define SCALE_ 0.125f   // DH^-0.5 = 1/8
#define QT 16
#define KT 64
// LDS half strides (in halves): data + pad, rows 16B-aligned
#define HQ 72     // Q: 64 + 8
#define HQP 56    // QP': 48 + 8
#define HK 72     // K: 64 + 8
#define HKP 56    // KP': 48 + 8
#define HV 112    // V|VP: 112 (224B, aligned, no pad needed)
#define HW 72     // weights: 64 + 8

// ---------------------------------------------------------------- helpers
__device__ __forceinline__ float waveReduceSum(float v) {
#pragma unroll
    for (int o = 32; o; o >>= 1) v += __shfl_down(v, o, 64);
    return v;
}
// 8-dim fp16 dot (a,b = 4 half2), fp32 accumulate; compiler folds cvt into v_fma_mix
__device__ __forceinline__ float dot8h(const __half2* a, const __half2* b, float acc) {
#pragma unroll
    for (int i = 0; i < 4; i++) {
        acc = fmaf(__low2float(a[i]),  __low2float(b[i]),  acc);
        acc = fmaf(__high2float(a[i]), __high2float(b[i]), acc);
    }
    return acc;
}

// ---------------------------------------------------------------- kernel 1: LN (LN1 and LN2)
__global__ __launch_bounds__(256) void ln1_kernel(
    const float* __restrict__ x, const float* __restrict__ g,
    const float* __restrict__ b, float* __restrict__ xn) {
    const int row = blockIdx.x;
    const int t = threadIdx.x;
    const float* xr = x + row * D_;
    float x0 = xr[t], x1 = xr[t + 256];
    __shared__ float red[4];
    float s = waveReduceSum(x0 + x1);
    int lane = t & 63, wid = t >> 6;
    if (lane == 0) red[wid] = s;
    __syncthreads();
    float mean = (red[0] + red[1] + red[2] + red[3]) * (1.0f / D_);
    __syncthreads();
    float d0 = x0 - mean, d1 = x1 - mean;
    float v = waveReduceSum(d0 * d0 + d1 * d1);
    if (lane == 0) red[wid] = v;
    __syncthreads();
    float var = (red[0] + red[1] + red[2] + red[3]) * (1.0f / D_);
    float rs = rsqrtf(var + 1e-5f);
    xn[row * D_ + t]       = d0 * rs * g[t] + b[t];
    xn[row * D_ + t + 256] = d1 * rs * g[t + 256] + b[t + 256];
}

// ---------------------------------------------------------------- kernel 2: projections GEMM
// Epilogue writes fp16 copies ONCE (R8 lesson: never convert per-tile in attn):
//  qh,kh: [row][512] fp16 ; qph,kph: [row][384] fp16 = raw + bias (NO coords);
//  vch:   [row][H*112] fp16 (v | vp per head).
__global__ __launch_bounds__(256) void proj_kernel(
    const float* __restrict__ xn, const float* __restrict__ coords,
    const float* __restrict__ Wq, const float* __restrict__ Wk, const float* __restrict__ Wv,
    const float* __restrict__ Wqp, const float* __restrict__ bqp,
    const float* __restrict__ Wkp, const float* __restrict__ bkp,
    const float* __restrict__ Wvp, const float* __restrict__ bvp,
    __half* __restrict__ qh, __half* __restrict__ kh, __half* __restrict__ vch,
    __half* __restrict__ qph, __half* __restrict__ kph) {
    const int tid = threadIdx.x;
    const int rowBase = blockIdx.y * 64;
    const int colBase = blockIdx.x * 64;

    const float* Wseg; int ldw, segBase, segId;
    if      (colBase < 512)  { Wseg = Wq;  ldw = D_;   segBase = 0;    segId = 0; }
    else if (colBase < 1024) { Wseg = Wk;  ldw = D_;   segBase = 512;  segId = 1; }
    else if (colBase < 1536) { Wseg = Wv;  ldw = D_;   segBase = 1024; segId = 2; }
    else if (colBase < 1920) { Wseg = Wqp; ldw = HP3_; segBase = 1536; segId = 3; }
    else if (colBase < 2304) { Wseg = Wkp; ldw = HP3_; segBase = 1920; segId = 4; }
    else                     { Wseg = Wvp; ldw = HP3_; segBase = 2304; segId = 5; }
    const int segc0 = colBase - segBase;

    __shared__ float As[16][65];
    __shared__ float Bs[16][64];
    const int tx = tid & 15, ty = tid >> 4;

    float acc[4][4];
#pragma unroll
    for (int i = 0; i < 4; i++)
#pragma unroll
        for (int j = 0; j < 4; j++) acc[i][j] = 0.f;

    for (int k0 = 0; k0 < D_; k0 += 16) {
#pragma unroll
        for (int i = 0; i < 4; i++) {
            int e = tid + i * 256;
            int r = e >> 4, kk = e & 15;
            As[kk][r] = xn[(rowBase + r) * D_ + k0 + kk];
            int c = e & 63, kb = e >> 6;
            Bs[kb][c] = Wseg[(k0 + kb) * ldw + segc0 + c];
        }
        __syncthreads();
#pragma unroll
        for (int kk = 0; kk < 16; kk++) {
            float a[4], bb[4];
#pragma unroll
            for (int i = 0; i < 4; i++) a[i] = As[kk][ty * 4 + i];
#pragma unroll
            for (int j = 0; j < 4; j++) bb[j] = Bs[kk][tx * 4 + j];
#pragma unroll
            for (int i = 0; i < 4; i++)
#pragma unroll
                for (int j = 0; j < 4; j++) acc[i][j] = fmaf(a[i], bb[j], acc[i][j]);
        }
        __syncthreads();
    }

    const int lc0 = segc0 + tx * 4;   // 4-aligned; never crosses 48/64 head boundaries
#pragma unroll
    for (int i = 0; i < 4; i++) {
        int r = rowBase + ty * 4 + i;
        float v0 = acc[i][0], v1 = acc[i][1], v2 = acc[i][2], v3 = acc[i][3];
        __half2* dst;
        switch (segId) {
            case 0: dst = (__half2*)(qh + (size_t)r * D_ + lc0); break;
            case 1: dst = (__half2*)(kh + (size_t)r * D_ + lc0); break;
            case 2: { int hh = lc0 >> 6, d = lc0 & 63;
                      dst = (__half2*)(vch + (size_t)r * (H_*112) + hh * 112 + d); break; }
            case 3: v0 += bqp[lc0]; v1 += bqp[lc0+1]; v2 += bqp[lc0+2]; v3 += bqp[lc0+3];
                    dst = (__half2*)(qph + (size_t)r * HP3_ + lc0); break;
            case 4: v0 += bkp[lc0]; v1 += bkp[lc0+1]; v2 += bkp[lc0+2]; v3 += bkp[lc0+3];
                    dst = (__half2*)(kph + (size_t)r * HP3_ + lc0); break;
            default: { v0 += bvp[lc0]; v1 += bvp[lc0+1]; v2 += bvp[lc0+2]; v3 += bvp[lc0+3];
                      int hh = lc0 / 48, d = lc0 % 48;
                      dst = (__half2*)(vch + (size_t)r * (H_*112) + hh * 112 + 64 + d); break; }
        }
        dst[0] = __floats2half2_rn(v0, v1);
        dst[1] = __floats2half2_rn(v2, v3);
    }
}

// ---------------------------------------------------------------- kernel 3: per-(row,h) stats
// qstat/kstat[row*H+h] = {s0,s1,s2, A} with s = sum_p p', A = -0.5*sum p'^2 - c.s
__global__ __launch_bounds__(256) void stat_kernel(
    const __half* __restrict__ qph, const __half* __restrict__ kph,
    const float* __restrict__ coords,
    float* __restrict__ qstat, float* __restrict__ kstat) {
    int idx = blockIdx.x * 256 + threadIdx.x;      // 16384
    int row = idx >> 3, h = idx & 7;
    float c0 = coords[row*3], c1 = coords[row*3+1], c2 = coords[row*3+2];
    const __half* qp = qph + (size_t)row * HP3_ + h * 48;
    const __half* kp = kph + (size_t)row * HP3_ + h * 48;
    float s0=0,s1=0,s2=0,n=0;
#pragma unroll
    for (int p = 0; p < 16; p++) {
        float a0 = __half2float(qp[p*3]), a1 = __half2float(qp[p*3+1]), a2 = __half2float(qp[p*3+2]);
        s0 += a0; s1 += a1; s2 += a2;
        n = fmaf(a0,a0,fmaf(a1,a1,fmaf(a2,a2,n)));
    }
    float4* qs4 = (float4*)(qstat + idx*4);
    *qs4 = make_float4(s0, s1, s2, -0.5f*n - (c0*s0 + c1*s1 + c2*s2));
    s0=0; s1=0; s2=0; n=0;
#pragma unroll
    for (int p = 0; p < 16; p++) {
        float a0 = __half2float(kp[p*3]), a1 = __half2float(kp[p*3+1]), a2 = __half2float(kp[p*3+2]);
        s0 += a0; s1 += a1; s2 += a2;
        n = fmaf(a0,a0,fmaf(a1,a1,fmaf(a2,a2,n)));
    }
    float4* ks4 = (float4*)(kstat + idx*4);
    *ks4 = make_float4(s0, s1, s2, -0.5f*n - (c0*s0 + c1*s1 + c2*s2));
}

// ---------------------------------------------------------------- kernel 4: flash attention, fp16 LDS, QT=16
// R11 lesson: FULL unroll of the qk/pd dot loops batched ~256 LDS loads ->
// register-pressure explosion -> scratch spill (1.5GB writes) even at VGPR=128.
// Fix: partial unrolls (R8's proven pressure: unroll 2 on d8 loops, 4 on MLP).
__global__ __launch_bounds__(256, 2) void attn_kernel(
    const __half* __restrict__ qh, const __half* __restrict__ kh, const __half* __restrict__ vch,
    const __half* __restrict__ qph, const __half* __restrict__ kph,
    const float* __restrict__ qstat, const float* __restrict__ kstat,
    const float* __restrict__ coords,
    const float* __restrict__ Wd1, const float* __restrict__ bd1,
    const float* __restrict__ Wd2, const float* __restrict__ bd2,
    float* __restrict__ attn_out) {
    const int qt = blockIdx.x, h = blockIdx.y, b = blockIdx.z;
    const int tid = threadIdx.x;
    const int qr = tid >> 4;           // 0..15: this thread's q row
    const int sub = tid & 15;          // logits: key = sub+16j ; PV: dim-group
    const int qbase = qt * QT;
    const size_t bq = (size_t)(b * S_ + qbase);

    __shared__ __align__(16) __half sQh[QT * HQ];
    __shared__ __align__(16) __half sQPh[QT * HQP];
    __shared__ __align__(16) __half sKh[KT * HK];
    __shared__ __align__(16) __half sKPh[KT * HKP];
    __shared__ __align__(16) __half sVh[KT * HV];
    __shared__ __align__(16) __half sWh[QT * HW];
    __shared__ __align__(16) float  sKS[KT * 8];   // {ck0,ck1,ck2,-, ks0,ks1,ks2,Ak}
    __shared__ float sW1[32], sB1[32], sW2h[32];

    // ---- stage Q-side once (plain fp16 copies, no conversion)
    if (tid < 128) {      // 16 rows x 8 uint4 of Q
        int r = tid >> 3, c = tid & 7;
        ((uint4*)&sQh[r * HQ])[c] = ((const uint4*)(qh + (bq + r) * D_ + h * DH_))[c];
    } else if (tid < 224) {  // 96 = 16 rows x 6 uint4 of QP'
        int e = tid - 128;
        int r = e / 6, c = e % 6;
        ((uint4*)&sQPh[r * HQP])[c] = ((const uint4*)(qph + (bq + r) * HP3_ + h * 48))[c];
    } else if (tid < 256) {
        int e = tid - 224;   // 32
        sW1[e] = Wd1[e];
        sB1[e] = bd1[e];
        sW2h[e] = Wd2[e * H_ + h];
    }
    // per-thread q-side scalars
    const float4 qst = *(const float4*)(qstat + ((bq + qr) * H_ + h) * 4);
    const float cqx = coords[(bq + qr) * 3], cqy = coords[(bq + qr) * 3 + 1], cqz = coords[(bq + qr) * 3 + 2];
    const float bd2h = bd2[h];
    __syncthreads();

    float m = -3.0e38f, l = 0.f;
    float o[8] = {0,0,0,0,0,0,0,0};

    for (int kt = 0; kt < S_ / KT; kt++) {
        const size_t bk = (size_t)(b * S_ + kt * KT);
        // ---- stage K (2/thr), KP' (1.5/thr), V (3.5/thr), stats (tid<64)
#pragma unroll
        for (int i = 0; i < 2; i++) {
            int f4 = tid + i * 256;   // 512 = 64x8
            int r = f4 >> 3, c = f4 & 7;
            ((uint4*)&sKh[r * HK])[c] = ((const uint4*)(kh + (bk + r) * D_ + h * DH_))[c];
        }
#pragma unroll
        for (int i = 0; i < 2; i++) {
            int f4 = tid + i * 256;   // 384 = 64x6
            if (f4 < 384) {
                int r = f4 / 6, c = f4 % 6;
                ((uint4*)&sKPh[r * HKP])[c] = ((const uint4*)(kph + (bk + r) * HP3_ + h * 48))[c];
            }
        }
#pragma unroll
        for (int i = 0; i < 4; i++) {
            int f4 = tid + i * 256;   // 896 = 64x14
            if (f4 < 896) {
                int r = f4 / 14, c = f4 % 14;
                ((uint4*)&sVh[r * HV])[c] = ((const uint4*)(vch + (bk + r) * (H_*112) + h * 112))[c];
            }
        }
        if (tid < KT) {
            *(float4*)&sKS[tid * 8 + 4] = *(const float4*)(kstat + ((bk + tid) * H_ + h) * 4);
            sKS[tid * 8 + 0] = coords[(bk + tid) * 3];
            sKS[tid * 8 + 1] = coords[(bk + tid) * 3 + 1];
            sKS[tid * 8 + 2] = coords[(bk + tid) * 3 + 2];
        }
        __syncthreads();                  // SYNC-K

        // ---- per-key base term + dist (4 keys: sub+16j)
        float lg[4];
#pragma unroll
        for (int j = 0; j < 4; j++) {
            const int kk = sub + 16 * j;
            float4 c4 = *(const float4*)&sKS[kk * 8];
            float4 s4 = *(const float4*)&sKS[kk * 8 + 4];
            float dx = cqx - c4.x, dy = cqy - c4.y, dz = cqz - c4.z;
            float d2 = fmaf(dx, dx, fmaf(dy, dy, dz * dz));
            float dist = sqrtf(d2);
            // dist-MLP bias
            float bias = bd2h;
#pragma unroll 4
            for (int jj = 0; jj < 32; jj++) {
                float hd = fmaf(dist, sW1[jj], sB1[jj]);
                bias = fmaf(fmaxf(hd, 0.f), sW2h[jj], bias);
            }
            // decomposed point base: Aq + Ak + cq.ks + ck.qs - 8 d2
            float base = qst.w + s4.w
                       + cqx * s4.x + cqy * s4.y + cqz * s4.z
                       + c4.x * qst.x + c4.y * qst.y + c4.z * qst.z
                       - 8.0f * d2 + bias;
            lg[j] = (dist < CUTOFF) ? base : -1e9f;
        }
        // ---- qk dot (fp16 x fp16 -> fp32 via fma_mix); PARTIAL unroll (R11 spill fix)
        {
            const __half2* q2 = (const __half2*)&sQh[qr * HQ];
            float acc[4] = {0,0,0,0};
#pragma unroll 2
            for (int d8 = 0; d8 < 8; d8++) {
#pragma unroll
                for (int j = 0; j < 4; j++) {
                    const __half2* k2 = (const __half2*)&sKh[(sub + 16 * j) * HK];
                    acc[j] = dot8h(q2 + d8 * 4, k2 + d8 * 4, acc[j]);
                }
            }
            const __half2* p2 = (const __half2*)&sQPh[qr * HQP];
            float pda[4] = {0,0,0,0};
#pragma unroll 2
            for (int d8 = 0; d8 < 6; d8++) {
#pragma unroll
                for (int j = 0; j < 4; j++) {
                    const __half2* kp2 = (const __half2*)&sKPh[(sub + 16 * j) * HKP];
                    pda[j] = dot8h(p2 + d8 * 4, kp2 + d8 * 4, pda[j]);
                }
            }
#pragma unroll
            for (int j = 0; j < 4; j++)
                if (lg[j] != -1e9f) lg[j] += fmaf(SCALE_, acc[j], pda[j]);
        }
        // ---- wave-local online softmax (16-lane group shares q row)
        float t0 = fmaxf(fmaxf(lg[0], lg[1]), fmaxf(lg[2], lg[3]));
#pragma unroll
        for (int off = 1; off < 16; off <<= 1) t0 = fmaxf(t0, __shfl_xor(t0, off, 16));
        const float nm = fmaxf(m, t0);
        const float sc = __expf(m - nm);
        m = nm;
        float ps = 0.f;
        __half* wrow = &sWh[qr * HW];
#pragma unroll
        for (int j = 0; j < 4; j++) {
            float w = __expf(lg[j] - nm);
            wrow[sub + 16 * j] = __float2half(w);   // same-wave write/read
            ps += w;
        }
#pragma unroll
        for (int off = 1; off < 16; off <<= 1) ps += __shfl_xor(ps, off, 16);
        l = l * sc + ps;

        // ---- PV: 1 q x 8 dims per thread (sub<14), fp16 V + fp16 w
#pragma unroll
        for (int j = 0; j < 8; j++) o[j] *= sc;
        if (sub < 14) {
            const int db = sub * 8;
            for (int kk4 = 0; kk4 < 16; kk4++) {
                __half2 w01 = ((const __half2*)wrow)[kk4 * 2];
                __half2 w23 = ((const __half2*)wrow)[kk4 * 2 + 1];
                float wf[4] = { __low2float(w01), __high2float(w01),
                                __low2float(w23), __high2float(w23) };
#pragma unroll
                for (int jj = 0; jj < 4; jj++) {
                    const __half2* v2 = (const __half2*)&sVh[(kk4 * 4 + jj) * HV + db];
                    float w = wf[jj];
                    o[0] = fmaf(w, __low2float(v2[0]),  o[0]);
                    o[1] = fmaf(w, __high2float(v2[0]), o[1]);
                    o[2] = fmaf(w, __low2float(v2[1]),  o[2]);
                    o[3] = fmaf(w, __high2float(v2[1]), o[3]);
                    o[4] = fmaf(w, __low2float(v2[2]),  o[4]);
                    o[5] = fmaf(w, __high2float(v2[2]), o[5]);
                    o[6] = fmaf(w, __low2float(v2[3]),  o[6]);
                    o[7] = fmaf(w, __high2float(v2[3]), o[7]);
                }
            }
        }
        __syncthreads();                  // SYNC-C (next staging overwrites)
    }

    // ---- epilogue
    if (sub < 14) {
        const int db = sub * 8;
        const float il = 1.0f / l;
        const int off = (db < 64) ? (h * 64 + db) : (512 + h * 48 + (db - 64));
        float* r0 = attn_out + (size_t)(bq + qr) * CONCAT_ + off;
        float4 a, bqt;
        a.x = o[0]*il; a.y = o[1]*il; a.z = o[2]*il; a.w = o[3]*il;
        bqt.x = o[4]*il; bqt.y = o[5]*il; bqt.z = o[6]*il; bqt.w = o[7]*il;
        *(float4*)r0 = a; *(float4*)(r0 + 4) = bqt;
    }
}

// ---------------------------------------------------------------- kernel 5: out projection GEMM (+bias+residual)
__global__ __launch_bounds__(256) void ogemm_kernel(
    const float* __restrict__ aout, const float* __restrict__ x,
    const float* __restrict__ Wo, const float* __restrict__ bo,
    float* __restrict__ yres) {
    const int tid = threadIdx.x;
    const int rowBase = blockIdx.y * 64;
    const int colBase = blockIdx.x * 64;

    __shared__ float As[16][65];
    __shared__ float Bs[16][64];
    const int tx = tid & 15, ty = tid >> 4;

    float acc[4][4];
#pragma unroll
    for (int i = 0; i < 4; i++)
#pragma unroll
        for (int j = 0; j < 4; j++) acc[i][j] = 0.f;

    for (int k0 = 0; k0 < CONCAT_; k0 += 16) {
#pragma unroll
        for (int i = 0; i < 4; i++) {
            int e = tid + i * 256;
            int r = e >> 4, kk = e & 15;
            As[kk][r] = aout[(size_t)(rowBase + r) * CONCAT_ + k0 + kk];
            int c = e & 63, kb = e >> 6;
            Bs[kb][c] = Wo[(k0 + kb) * D_ + colBase + c];
        }
        __syncthreads();
#pragma unroll
        for (int kk = 0; kk < 16; kk++) {
            float a[4], bb[4];
#pragma unroll
            for (int i = 0; i < 4; i++) a[i] = As[kk][ty * 4 + i];
#pragma unroll
            for (int j = 0; j < 4; j++) bb[j] = Bs[kk][tx * 4 + j];
#pragma unroll
            for (int i = 0; i < 4; i++)
#pragma unroll
                for (int j = 0; j < 4; j++) acc[i][j] = fmaf(a[i], bb[j], acc[i][j]);
        }
        __syncthreads();
    }

#pragma unroll
    for (int i = 0; i < 4; i++) {
        int r = rowBase + ty * 4 + i;
#pragma unroll
        for (int j = 0; j < 4; j++) {
            int lc = colBase + tx * 4 + j;
            yres[(size_t)r * D_ + lc] = acc[i][j] + bo[lc] + x[(size_t)r * D_ + lc];
        }
    }
}

// ---------------------------------------------------------------- kernel 6: coord update
__global__ __launch_bounds__(64) void coord_kernel(
    const float* __restrict__ aout, const float* __restrict__ coords,
    float* __restrict__ coords_out) {
    const int row = blockIdx.x;
    const int t = threadIdx.x;
    const float* ap = aout + (size_t)row * CONCAT_ + 512;
    float c0 = ap[t * 3]     + ap[(t + 64) * 3];
    float c1 = ap[t * 3 + 1] + ap[(t + 64) * 3 + 1];
    float c2 = ap[t * 3 + 2] + ap[(t + 64) * 3 + 2];
#pragma unroll
    for (int o = 32; o; o >>= 1) {
        c0 += __shfl_down(c0, o, 64);
        c1 += __shfl_down(c1, o, 64);
        c2 += __shfl_down(c2, o, 64);
    }
    if (t == 0) {
        coords_out[row * 3 + 0] = coords[row * 3 + 0] + c0 * (0.1f / 128.f);
        coords_out[row * 3 + 1] = coords[row * 3 + 1] + c1 * (0.1f / 128.f);
        coords_out[row * 3 + 2] = coords[row * 3 + 2] + c2 * (0.1f / 128.f);
    }
}

// ---------------------------------------------------------------- launch
extern "C" void kernel_launch(void* const* d_in, const int* in_sizes, int n_in,
                              void* d_out, int out_size, void* d_ws, size_t ws_size,
                              hipStream_t stream) {
    const float* x      = (const float*)d_in[0];
    const float* coords = (const float*)d_in[1];
    const float* Wq     = (const float*)d_in[2];
    const float* Wk     = (const float*)d_in[3];
    const float* Wv     = (const float*)d_in[4];
    const float* Wqp    = (const float*)d_in[5];
    const float* bqp    = (const float*)d_in[6];
    const float* Wkp    = (const float*)d_in[7];
    const float* bkp    = (const float*)d_in[8];
    const float* Wvp    = (const float*)d_in[9];
    const float* bvp    = (const float*)d_in[10];
    const float* Wd1    = (const float*)d_in[11];
    const float* bd1    = (const float*)d_in[12];
    const float* Wd2    = (const float*)d_in[13];
    const float* bd2    = (const float*)d_in[14];
    const float* Wo     = (const float*)d_in[15];
    const float* bo     = (const float*)d_in[16];
    const float* g1     = (const float*)d_in[17];
    const float* b1     = (const float*)d_in[18];
    const float* g2     = (const float*)d_in[19];
    const float* b2     = (const float*)d_in[20];

    float* out        = (float*)d_out;
    float* coords_out = (float*)d_out + (size_t)B_ * S_ * D_;

    const size_t NROW = (size_t)B_ * S_;
    float* ws    = (float*)d_ws;
    float* xn    = ws;                            // NROW*512 f32 (reused as yres)
    float* aout  = xn + NROW * D_;                // NROW*896 f32
    __half* qh   = (__half*)(aout + NROW * CONCAT_);   // NROW*512 fp16
    __half* kh   = qh  + NROW * D_;
    __half* qph  = kh  + NROW * D_;               // NROW*384
    __half* kph  = qph + NROW * HP3_;
    __half* vch  = kph + NROW * HP3_;             // NROW*896
    float* qstat = (float*)(vch + NROW * (H_*112));    // NROW*8*4 f32
    float* kstat = qstat + NROW * H_ * 4;

    ln1_kernel<<<NROW, 256, 0, stream>>>(x, g1, b1, xn);

    dim3 pgrid(2688 / 64, 2048 / 64);
    proj_kernel<<<pgrid, 256, 0, stream>>>(xn, coords, Wq, Wk, Wv,
                                           Wqp, bqp, Wkp, bkp, Wvp, bvp,
                                           qh, kh, vch, qph, kph);

    stat_kernel<<<(NROW * H_) / 256, 256, 0, stream>>>(qph, kph, coords, qstat, kstat);

    dim3 agrid(S_ / QT, H_, B_);
    attn_kernel<<<agrid, 256, 0, stream>>>(qh, kh, vch, qph, kph, qstat, kstat,
                                           coords, Wd1, bd1, Wd2, bd2, aout);

    float* yres = xn;
    dim3 ogrid(D_ / 64, 2048 / 64);
    ogemm_kernel<<<ogrid, 256, 0, stream>>>(aout, x, Wo, bo, yres);

    ln1_kernel<<<NROW, 256, 0, stream>>>(yres, g2, b2, out);

    coord_kernel<<<NROW, 64, 0, stream>>>(aout, coords, coords_out);
}